// Round 15
// baseline (64.140 us; speedup 1.0000x reference)
//
#include <hip/hip_runtime.h>

#define NB 2
#define SQL 256
#define NH 16
#define HD 64
#define EMB 1024

typedef unsigned short ushortT;
typedef unsigned int uintT;
typedef __attribute__((ext_vector_type(8))) short bf16x8;
typedef __attribute__((ext_vector_type(4))) float f32x4;
typedef __attribute__((ext_vector_type(2))) float f32x2;

// log2(e) / sqrt(EMBED): folded into Wq so softmax = 2^(q*k)
__device__ __constant__ float kQSCALE = 1.4426950408889634f / 32.0f;

__device__ __forceinline__ float fexp2(float x) { return __builtin_amdgcn_exp2f(x); }
__device__ __forceinline__ float frcp(float x)  { return __builtin_amdgcn_rcpf(x); }

__device__ __forceinline__ ushortT f2bf(float x) {
    uintT u = __float_as_uint(x);
    u += 0x7fffu + ((u >> 16) & 1u);        // RNE
    return (ushortT)(u >> 16);
}
__device__ __forceinline__ ushort4 f2bf4(float4 a) {
    return make_ushort4(f2bf(a.x), f2bf(a.y), f2bf(a.z), f2bf(a.w));
}
// unpack one uint32 = 2 bf16 (lo = even channel, hi = odd channel) -> f32x2
__device__ __forceinline__ f32x2 unpk2(uintT u) {
    f32x2 r;
    r.x = __uint_as_float(u << 16);
    r.y = __uint_as_float(u & 0xffff0000u);
    return r;
}
// pair-sum via DPP quad_perm [1,0,3,2]: lane(2i) <-> lane(2i+1). VALU pipe.
__device__ __forceinline__ float pairsum_dpp(float u) {
    const int j = __builtin_amdgcn_mov_dpp(__float_as_int(u), 0xB1, 0xF, 0xF, true);
    return u + __int_as_float(j);
}

// ---------------------------------------------------------------------------
// Kernel 1: q/k/v projections via bf16 MFMA (16x16x32). Block = 2 (n,s) rows.
// Folds: AO=0, out=bias init, Wo -> bf16 (Wob). Grid 256 x 256.
// ---------------------------------------------------------------------------
__global__ __launch_bounds__(256) void qkv_kernel(
    const float* __restrict__ x,
    const float* __restrict__ Wq,
    const float* __restrict__ Wk,
    const float* __restrict__ Wv,
    const float* __restrict__ Wo,
    const float* __restrict__ bo,
    ushortT* __restrict__ Q,
    ushortT* __restrict__ K,
    ushortT* __restrict__ V,
    float* __restrict__ AO,
    float* __restrict__ out,
    ushortT* __restrict__ Wob)
{
    __shared__ ushortT wls[3][64 * 72];
    __shared__ ushortT xs[2][16 * 72];

    const int tid = threadIdx.x;
    const int ns0 = blockIdx.x * 2;
    const int g   = blockIdx.x * 256 + tid;   // 65536 threads total

    {
        const float4 z = make_float4(0.f, 0.f, 0.f, 0.f);
        ((float4*)AO)[g] = z;
        ((float4*)AO)[g + 65536] = z;
        const float4 bb = ((const float4*)bo)[g & 255];
        ((float4*)out)[g] = bb;
        ((float4*)out)[g + 65536] = bb;
    }
#pragma unroll
    for (int j = 0; j < 4; ++j) {
        const int f4 = j * 65536 + g;
        ((ushort4*)Wob)[f4] = f2bf4(((const float4*)Wo)[f4]);
    }

#pragma unroll
    for (int m = 0; m < 3; ++m) {
        const float4* src = (m == 0) ? (const float4*)Wq
                          : (m == 1) ? (const float4*)Wk : (const float4*)Wv;
#pragma unroll
        for (int j = 0; j < 4; ++j) {
            const int idx = j * 256 + tid;
            const int e   = idx >> 4;
            const int d4  = idx & 15;
            float4 a = src[idx];
            if (m == 0) { a.x *= kQSCALE; a.y *= kQSCALE; a.z *= kQSCALE; a.w *= kQSCALE; }
            *(ushort4*)&wls[m][e * 72 + d4 * 4] = f2bf4(a);
        }
    }
#pragma unroll
    for (int j = 0; j < 2; ++j) {
        const int idx = j * 256 + tid;
        const int r   = idx >> 8;
        const int h   = (idx >> 4) & 15;
        const int d4  = idx & 15;
        const float4 a = ((const float4*)(x + (size_t)(ns0 + r) * EMB))[idx & 255];
        *(ushort4*)&xs[r][h * 72 + d4 * 4] = f2bf4(a);
    }
    __syncthreads();

    const int w   = tid >> 6;
    const int nsr = w >> 1;
    const int eb0 = (w & 1) * 32;
    const int l   = tid & 63;
    const int lr  = l & 15;
    const int lk  = l >> 4;

    const bf16x8 a0 = *(const bf16x8*)&xs[nsr][lr * 72 + lk * 8];
    const bf16x8 a1 = *(const bf16x8*)&xs[nsr][lr * 72 + 32 + lk * 8];

#pragma unroll
    for (int m = 0; m < 3; ++m) {
        ushortT* outp = (m == 0) ? Q : (m == 1) ? K : V;
#pragma unroll
        for (int ef = 0; ef < 2; ++ef) {
            const int eb = eb0 + ef * 16;
            const bf16x8 b0 = *(const bf16x8*)&wls[m][(eb + lr) * 72 + lk * 8];
            const bf16x8 b1 = *(const bf16x8*)&wls[m][(eb + lr) * 72 + 32 + lk * 8];
            f32x4 c = {0.f, 0.f, 0.f, 0.f};
            c = __builtin_amdgcn_mfma_f32_16x16x32_bf16(a0, b0, c, 0, 0, 0);
            c = __builtin_amdgcn_mfma_f32_16x16x32_bf16(a1, b1, c, 0, 0, 0);
            ushortT* dst = outp + (size_t)(ns0 + nsr) * EMB + (eb + lr) * 16 + lk * 4;
            *(ushort4*)dst = make_ushort4(f2bf(c[0]), f2bf(c[1]), f2bf(c[2]), f2bf(c[3]));
        }
    }
}

// ---------------------------------------------------------------------------
// Kernel 2: fused energy -> softmax(h) -> sum(t). Round-15 restructure:
// FOUR s-streams per wave (was 2) -> one K/V load+unpack feeds 4 softmax
// streams (2x fewer loads and unpacks per unit work; attn was load-latency
// bound, not issue-bound -- packed-math round proved it). Streams processed
// sequentially inside a step to cap liveness; packed f32x2 math throughout.
// Block = 4 waves x 4 s = 16 s; grid = 2n * 16sg * 2eh * 16tc = 1024
// (4 blocks/CU, 128-VGPR budget via launch_bounds(256,4)).
// ---------------------------------------------------------------------------
#define ATTN_STEP4(KU4, VU4)                                                   \
    {                                                                          \
        f32x2 ku[4], vu[4];                                                    \
        ku[0] = unpk2(KU4.x); ku[1] = unpk2(KU4.y);                            \
        ku[2] = unpk2(KU4.z); ku[3] = unpk2(KU4.w);                            \
        vu[0] = unpk2(VU4.x); vu[1] = unpk2(VU4.y);                            \
        vu[2] = unpk2(VU4.z); vu[3] = unpk2(VU4.w);                            \
        _Pragma("unroll")                                                      \
        for (int m = 0; m < 4; ++m) {                                          \
            f32x2 p[4];                                                        \
            _Pragma("unroll")                                                  \
            for (int j = 0; j < 4; ++j) {                                      \
                const f32x2 xq = q2[m][j] * ku[j];                             \
                p[j].x = fexp2(xq.x);                                          \
                p[j].y = fexp2(xq.y);                                          \
            }                                                                  \
            const f32x2 s = (p[0] + p[1]) + (p[2] + p[3]);                     \
            const float rs = frcp(pairsum_dpp(s.x + s.y));                     \
            const f32x2 rb = {rs, rs};                                         \
            _Pragma("unroll")                                                  \
            for (int j = 0; j < 4; ++j)                                        \
                acc[m][j] = __builtin_elementwise_fma(vu[j] * rb, p[j], acc[m][j]); \
        }                                                                      \
    }

__global__ __launch_bounds__(256, 4) void attn_kernel(
    const ushortT* __restrict__ Q,
    const ushortT* __restrict__ K,
    const ushortT* __restrict__ V,
    float* __restrict__ AO)
{
    const int b    = blockIdx.x;
    const int tc   = b & 15;
    const int eh   = (b >> 4) & 1;
    const int sg   = (b >> 5) & 15;
    const int n    = b >> 9;
    const int wave = threadIdx.x >> 6;
    const int l    = threadIdx.x & 63;
    const int s0   = sg * 16 + wave * 4;
    const int t0   = tc * 16;

    f32x2 q2[4][4];
    {
        const uint4* qp = (const uint4*)(Q + (size_t)(n * SQL + s0) * EMB + 512 * eh) + l;
#pragma unroll
        for (int m = 0; m < 4; ++m) {
            const uint4 qa = qp[m * 128];   // s row stride = 128 uint4
            q2[m][0] = unpk2(qa.x); q2[m][1] = unpk2(qa.y);
            q2[m][2] = unpk2(qa.z); q2[m][3] = unpk2(qa.w);
        }
    }

    f32x2 acc[4][4];
#pragma unroll
    for (int m = 0; m < 4; ++m)
#pragma unroll
        for (int j = 0; j < 4; ++j) acc[m][j] = (f32x2){0.f, 0.f};

    const uint4* kp = (const uint4*)(K + (size_t)(n * SQL + t0) * EMB + 512 * eh) + l;
    const uint4* vp = (const uint4*)(V + (size_t)(n * SQL + t0) * EMB + 512 * eh) + l;

    uint4 ka = kp[0], va = vp[0];          // t
    uint4 kb = kp[128], vb = vp[128];      // t+1

#pragma unroll
    for (int tt = 0; tt < 16; tt += 2) {
        ATTN_STEP4(ka, va);                // consume t
        ka = kp[256]; va = vp[256];        // t+2 (tail over-read: safe, adjacent ws)
        ATTN_STEP4(kb, vb);                // consume t+1
        kb = kp[384]; vb = vp[384];        // t+3 (tail over-read: safe)
        kp += 256; vp += 256;
    }

    // element = 512eh + 8l + c  ->  e = 32eh+(l>>1), h = 8(l&1)+c
    // AO channel = h*64 + e = 512(l&1) + 64c + 32eh + (l>>1)
    float* base = AO + (size_t)(n * SQL + s0) * EMB + 512 * (l & 1) + 32 * eh + (l >> 1);
#pragma unroll
    for (int m = 0; m < 4; ++m) {
        float* bm = base + (size_t)m * EMB;
#pragma unroll
        for (int j = 0; j < 4; ++j) {
            atomicAdd(bm + 64 * (2 * j),     acc[m][j].x);
            atomicAdd(bm + 64 * (2 * j + 1), acc[m][j].y);
        }
    }
}

// ---------------------------------------------------------------------------
// Kernel 3: out += AO @ Wob^T via bf16 MFMA. 64r x 128j tile, 512 threads
// (8 waves = 2x4 grid of 32x32 quadrants), k-split 4 -> f32 atomicAdd into
// bias-initialized out. Grid = 8rt * 8jt * 4kc = 256 blocks.
// ---------------------------------------------------------------------------
__global__ __launch_bounds__(512) void proj_kernel(
    const float* __restrict__ AO,
    const ushortT* __restrict__ Wob,
    float* __restrict__ out)
{
    __shared__ ushortT As[64 * 40];
    __shared__ ushortT Bs[128 * 40];

    const int b  = blockIdx.x;
    const int kc = b & 3;
    const int jt = (b >> 2) & 7;
    const int rt = b >> 5;
    const int tid = threadIdx.x;
    const int r0 = rt * 64, j0 = jt * 128, k0 = kc * 256;

    const int w  = tid >> 6;        // 0..7
    const int wr = w >> 2;          // 0..1
    const int wc = w & 3;           // 0..3
    const int l  = tid & 63;
    const int lr = l & 15;
    const int lk = l >> 4;

    f32x4 c00 = {0.f, 0.f, 0.f, 0.f};
    f32x4 c01 = {0.f, 0.f, 0.f, 0.f};
    f32x4 c10 = {0.f, 0.f, 0.f, 0.f};
    f32x4 c11 = {0.f, 0.f, 0.f, 0.f};

    for (int kt = 0; kt < 8; ++kt) {
        const int kb = k0 + kt * 32;
        __syncthreads();
        {
            const int row = tid >> 3;
            const int kq  = tid & 7;
            const float4 a = *(const float4*)&AO[(size_t)(r0 + row) * EMB + kb + kq * 4];
            *(ushort4*)&As[row * 40 + kq * 4] = f2bf4(a);
        }
        {
            const int row = tid >> 2;
            const int ko  = tid & 3;
            const uint4 wv = *(const uint4*)&Wob[(size_t)(j0 + row) * EMB + kb + ko * 8];
            *(uint4*)&Bs[row * 40 + ko * 8] = wv;
        }
        __syncthreads();

        const bf16x8 a0 = *(const bf16x8*)&As[(wr * 32 + lr) * 40 + lk * 8];
        const bf16x8 a1 = *(const bf16x8*)&As[(wr * 32 + 16 + lr) * 40 + lk * 8];
        const bf16x8 b0 = *(const bf16x8*)&Bs[(wc * 32 + lr) * 40 + lk * 8];
        const bf16x8 b1 = *(const bf16x8*)&Bs[(wc * 32 + 16 + lr) * 40 + lk * 8];
        c00 = __builtin_amdgcn_mfma_f32_16x16x32_bf16(a0, b0, c00, 0, 0, 0);
        c01 = __builtin_amdgcn_mfma_f32_16x16x32_bf16(a0, b1, c01, 0, 0, 0);
        c10 = __builtin_amdgcn_mfma_f32_16x16x32_bf16(a1, b0, c10, 0, 0, 0);
        c11 = __builtin_amdgcn_mfma_f32_16x16x32_bf16(a1, b1, c11, 0, 0, 0);
    }

    const int rbase = r0 + wr * 32 + lk * 4;
    const int jbase = j0 + wc * 32 + lr;
#pragma unroll
    for (int e = 0; e < 4; ++e) {
        atomicAdd(&out[(size_t)(rbase + e) * EMB + jbase],           c00[e]);
        atomicAdd(&out[(size_t)(rbase + e) * EMB + jbase + 16],      c01[e]);
        atomicAdd(&out[(size_t)(rbase + 16 + e) * EMB + jbase],      c10[e]);
        atomicAdd(&out[(size_t)(rbase + 16 + e) * EMB + jbase + 16], c11[e]);
    }
}

extern "C" void kernel_launch(void* const* d_in, const int* in_sizes, int n_in,
                              void* d_out, int out_size, void* d_ws, size_t ws_size,
                              hipStream_t stream)
{
    const float* x  = (const float*)d_in[0];
    const float* Wq = (const float*)d_in[1];
    const float* Wk = (const float*)d_in[2];
    const float* Wv = (const float*)d_in[3];
    const float* Wo = (const float*)d_in[4];
    const float* bo = (const float*)d_in[5];

    float* ws = (float*)d_ws;
    ushortT* Q   = (ushortT*)ws;              // 524288 bf16 = 1 MB
    ushortT* K   = (ushortT*)(ws + 262144);   // 1 MB
    ushortT* V   = (ushortT*)(ws + 524288);   // 1 MB
    float*   AO  = ws + 786432;               // 524288 f32 = 2 MB
    ushortT* Wob = (ushortT*)(ws + 1310720);  // 1048576 bf16 = 2 MB

    qkv_kernel<<<256, 256, 0, stream>>>(x, Wq, Wk, Wv, Wo, bo, Q, K, V, AO,
                                        (float*)d_out, Wob);
    attn_kernel<<<1024, 256, 0, stream>>>(Q, K, V, AO);
    proj_kernel<<<256, 512, 0, stream>>>(AO, Wob, (float*)d_out);
}

// Round 16
// 50.037 us; speedup vs baseline: 1.2819x; 1.2819x over previous
//
#include <hip/hip_runtime.h>

#define NB 2
#define SQL 256
#define NH 16
#define HD 64
#define EMB 1024

typedef unsigned short ushortT;
typedef unsigned int uintT;
typedef __attribute__((ext_vector_type(8))) short bf16x8;
typedef __attribute__((ext_vector_type(4))) float f32x4;
typedef __attribute__((ext_vector_type(2))) float f32x2;

// log2(e) / sqrt(EMBED): folded into Wq so softmax = 2^(q*k)
__device__ __constant__ float kQSCALE = 1.4426950408889634f / 32.0f;

__device__ __forceinline__ float fexp2(float x) { return __builtin_amdgcn_exp2f(x); }
__device__ __forceinline__ float frcp(float x)  { return __builtin_amdgcn_rcpf(x); }

__device__ __forceinline__ ushortT f2bf(float x) {
    uintT u = __float_as_uint(x);
    u += 0x7fffu + ((u >> 16) & 1u);        // RNE
    return (ushortT)(u >> 16);
}
__device__ __forceinline__ ushort4 f2bf4(float4 a) {
    return make_ushort4(f2bf(a.x), f2bf(a.y), f2bf(a.z), f2bf(a.w));
}
// unpack one uint32 = 2 bf16 (lo = even channel, hi = odd channel) -> f32x2
__device__ __forceinline__ f32x2 unpk2(uintT u) {
    f32x2 r;
    r.x = __uint_as_float(u << 16);
    r.y = __uint_as_float(u & 0xffff0000u);
    return r;
}
// pair-sum via DPP quad_perm [1,0,3,2]: lane(2i) <-> lane(2i+1). VALU pipe.
__device__ __forceinline__ float pairsum_dpp(float u) {
    const int j = __builtin_amdgcn_mov_dpp(__float_as_int(u), 0xB1, 0xF, 0xF, true);
    return u + __int_as_float(j);
}

// ---------------------------------------------------------------------------
// Kernel 1: q/k/v projections via bf16 MFMA (16x16x32). Block = 2 (n,s) rows.
// Folds: AO=0, out=bias init, Wo -> bf16 (Wob). Grid 256 x 256.
// ---------------------------------------------------------------------------
__global__ __launch_bounds__(256) void qkv_kernel(
    const float* __restrict__ x,
    const float* __restrict__ Wq,
    const float* __restrict__ Wk,
    const float* __restrict__ Wv,
    const float* __restrict__ Wo,
    const float* __restrict__ bo,
    ushortT* __restrict__ Q,
    ushortT* __restrict__ K,
    ushortT* __restrict__ V,
    float* __restrict__ AO,
    float* __restrict__ out,
    ushortT* __restrict__ Wob)
{
    __shared__ ushortT wls[3][64 * 72];
    __shared__ ushortT xs[2][16 * 72];

    const int tid = threadIdx.x;
    const int ns0 = blockIdx.x * 2;
    const int g   = blockIdx.x * 256 + tid;   // 65536 threads total

    {
        const float4 z = make_float4(0.f, 0.f, 0.f, 0.f);
        ((float4*)AO)[g] = z;
        ((float4*)AO)[g + 65536] = z;
        const float4 bb = ((const float4*)bo)[g & 255];
        ((float4*)out)[g] = bb;
        ((float4*)out)[g + 65536] = bb;
    }
#pragma unroll
    for (int j = 0; j < 4; ++j) {
        const int f4 = j * 65536 + g;
        ((ushort4*)Wob)[f4] = f2bf4(((const float4*)Wo)[f4]);
    }

#pragma unroll
    for (int m = 0; m < 3; ++m) {
        const float4* src = (m == 0) ? (const float4*)Wq
                          : (m == 1) ? (const float4*)Wk : (const float4*)Wv;
#pragma unroll
        for (int j = 0; j < 4; ++j) {
            const int idx = j * 256 + tid;
            const int e   = idx >> 4;
            const int d4  = idx & 15;
            float4 a = src[idx];
            if (m == 0) { a.x *= kQSCALE; a.y *= kQSCALE; a.z *= kQSCALE; a.w *= kQSCALE; }
            *(ushort4*)&wls[m][e * 72 + d4 * 4] = f2bf4(a);
        }
    }
#pragma unroll
    for (int j = 0; j < 2; ++j) {
        const int idx = j * 256 + tid;
        const int r   = idx >> 8;
        const int h   = (idx >> 4) & 15;
        const int d4  = idx & 15;
        const float4 a = ((const float4*)(x + (size_t)(ns0 + r) * EMB))[idx & 255];
        *(ushort4*)&xs[r][h * 72 + d4 * 4] = f2bf4(a);
    }
    __syncthreads();

    const int w   = tid >> 6;
    const int nsr = w >> 1;
    const int eb0 = (w & 1) * 32;
    const int l   = tid & 63;
    const int lr  = l & 15;
    const int lk  = l >> 4;

    const bf16x8 a0 = *(const bf16x8*)&xs[nsr][lr * 72 + lk * 8];
    const bf16x8 a1 = *(const bf16x8*)&xs[nsr][lr * 72 + 32 + lk * 8];

#pragma unroll
    for (int m = 0; m < 3; ++m) {
        ushortT* outp = (m == 0) ? Q : (m == 1) ? K : V;
#pragma unroll
        for (int ef = 0; ef < 2; ++ef) {
            const int eb = eb0 + ef * 16;
            const bf16x8 b0 = *(const bf16x8*)&wls[m][(eb + lr) * 72 + lk * 8];
            const bf16x8 b1 = *(const bf16x8*)&wls[m][(eb + lr) * 72 + 32 + lk * 8];
            f32x4 c = {0.f, 0.f, 0.f, 0.f};
            c = __builtin_amdgcn_mfma_f32_16x16x32_bf16(a0, b0, c, 0, 0, 0);
            c = __builtin_amdgcn_mfma_f32_16x16x32_bf16(a1, b1, c, 0, 0, 0);
            ushortT* dst = outp + (size_t)(ns0 + nsr) * EMB + (eb + lr) * 16 + lk * 4;
            *(ushort4*)dst = make_ushort4(f2bf(c[0]), f2bf(c[1]), f2bf(c[2]), f2bf(c[3]));
        }
    }
}

// ---------------------------------------------------------------------------
// Kernel 2: fused energy -> softmax(h) -> sum(t). Round-14 inner loop
// (2 s-streams x 8ch, packed f32x2, DPP pair-sum, ping-pong prefetch).
// ROUND-16 RESTRUCTURE: the 4 waves of a block now share the SAME output
// scope (2 s-rows x eh) and split the t-range (32 steps each, tw=2 windows);
// partial accumulators are tree-reduced through LDS and ONE atomic set is
// issued per block -> lane-atomics drop 8.4M -> 1M (testing the hypothesis
// that the atomic drain at ~100 lane-atomics/cy IS the 36us attn floor).
// Grid = 2n * 128sg * 2eh * 2tw = 1024 blocks x 256 threads.
// ---------------------------------------------------------------------------
#define ATTN_STEP(KU4, VU4)                                                    \
    {                                                                          \
        f32x2 k2[4], v2[4], p0[4], p1[4];                                      \
        k2[0] = unpk2(KU4.x); k2[1] = unpk2(KU4.y);                            \
        k2[2] = unpk2(KU4.z); k2[3] = unpk2(KU4.w);                            \
        _Pragma("unroll")                                                      \
        for (int j = 0; j < 4; ++j) {                                          \
            const f32x2 x0 = q0_2[j] * k2[j];                                  \
            const f32x2 x1 = q1_2[j] * k2[j];                                  \
            p0[j].x = fexp2(x0.x); p0[j].y = fexp2(x0.y);                      \
            p1[j].x = fexp2(x1.x); p1[j].y = fexp2(x1.y);                      \
        }                                                                      \
        const f32x2 s0v = (p0[0] + p0[1]) + (p0[2] + p0[3]);                   \
        const f32x2 s1v = (p1[0] + p1[1]) + (p1[2] + p1[3]);                   \
        const float rs0 = frcp(pairsum_dpp(s0v.x + s0v.y));                    \
        const float rs1 = frcp(pairsum_dpp(s1v.x + s1v.y));                    \
        const f32x2 rb0 = {rs0, rs0};                                          \
        const f32x2 rb1 = {rs1, rs1};                                          \
        v2[0] = unpk2(VU4.x); v2[1] = unpk2(VU4.y);                            \
        v2[2] = unpk2(VU4.z); v2[3] = unpk2(VU4.w);                            \
        _Pragma("unroll")                                                      \
        for (int j = 0; j < 4; ++j) {                                          \
            acc0[j] = __builtin_elementwise_fma(v2[j] * rb0, p0[j], acc0[j]);  \
            acc1[j] = __builtin_elementwise_fma(v2[j] * rb1, p1[j], acc1[j]);  \
        }                                                                      \
    }

__global__ __launch_bounds__(256) void attn_kernel(
    const ushortT* __restrict__ Q,
    const ushortT* __restrict__ K,
    const ushortT* __restrict__ V,
    float* __restrict__ AO)
{
    __shared__ float red[16][256];   // 16 KB, bank-conflict-free (bank = l%32)

    const int b    = blockIdx.x;
    const int tw   = b & 1;
    const int eh   = (b >> 1) & 1;
    const int sg   = (b >> 2) & 127;
    const int n    = b >> 9;
    const int wave = threadIdx.x >> 6;
    const int l    = threadIdx.x & 63;
    const int s0   = sg * 2;
    const int t0   = tw * 128 + wave * 32;   // each wave: 32 t-steps

    f32x2 q0_2[4], q1_2[4];
    {
        const uint4* qp = (const uint4*)(Q + (size_t)(n * SQL + s0) * EMB + 512 * eh) + l;
        const uint4 qa = qp[0];
        const uint4 qb = qp[128];   // next s row
        q0_2[0] = unpk2(qa.x); q0_2[1] = unpk2(qa.y);
        q0_2[2] = unpk2(qa.z); q0_2[3] = unpk2(qa.w);
        q1_2[0] = unpk2(qb.x); q1_2[1] = unpk2(qb.y);
        q1_2[2] = unpk2(qb.z); q1_2[3] = unpk2(qb.w);
    }

    f32x2 acc0[4], acc1[4];
#pragma unroll
    for (int j = 0; j < 4; ++j) {
        acc0[j] = (f32x2){0.f, 0.f};
        acc1[j] = (f32x2){0.f, 0.f};
    }

    const uint4* kp = (const uint4*)(K + (size_t)(n * SQL + t0) * EMB + 512 * eh) + l;
    const uint4* vp = (const uint4*)(V + (size_t)(n * SQL + t0) * EMB + 512 * eh) + l;

    uint4 ka = kp[0];      // k(t)
    uint4 kb = kp[128];    // k(t+1)
    uint4 va = vp[0];      // v(t)

#pragma unroll
    for (int tt = 0; tt < 32; tt += 2) {
        const uint4 kn2 = kp[256];   // k(t+2)
        const uint4 vb  = vp[128];   // v(t+1)
        ATTN_STEP(ka, va);           // consume t
        const uint4 kn3 = kp[384];   // k(t+3) (tail over-read: safe, adjacent ws)
        va = vp[256];                // v(t+2) (tail over-read: safe)
        kp += 256; vp += 256;
        ATTN_STEP(kb, vb);           // consume t+1
        ka = kn2; kb = kn3;
    }

    // ---- cross-wave LDS reduction: value i = s*8 + c (s in {0,1}, c in 0..7)
#pragma unroll
    for (int j = 0; j < 4; ++j) {
        red[2 * j    ][wave * 64 + l] = acc0[j].x;
        red[2 * j + 1][wave * 64 + l] = acc0[j].y;
        red[8 + 2 * j    ][wave * 64 + l] = acc1[j].x;
        red[8 + 2 * j + 1][wave * 64 + l] = acc1[j].y;
    }
    __syncthreads();

    // element = 512eh + 8l + cpair -> e = 32eh+(l>>1), h = 8(l&1)+c
    // AO channel = h*64 + e = 512(l&1) + 64c + 32eh + (l>>1)
    float* aob = AO + (size_t)(n * SQL + s0) * EMB + 512 * (l & 1) + 32 * eh + (l >> 1);
#pragma unroll
    for (int di = 0; di < 4; ++di) {
        const int i = wave * 4 + di;
        const float sum = (red[i][l] + red[i][64 + l]) + (red[i][128 + l] + red[i][192 + l]);
        const int s = i >> 3;
        const int c = i & 7;
        atomicAdd(aob + (size_t)s * EMB + 64 * c, sum);
    }
}

// ---------------------------------------------------------------------------
// Kernel 3: out += AO @ Wob^T via bf16 MFMA. 64r x 128j tile, 512 threads
// (8 waves = 2x4 grid of 32x32 quadrants), k-split 4 -> f32 atomicAdd into
// bias-initialized out. Grid = 8rt * 8jt * 4kc = 256 blocks.
// ---------------------------------------------------------------------------
__global__ __launch_bounds__(512) void proj_kernel(
    const float* __restrict__ AO,
    const ushortT* __restrict__ Wob,
    float* __restrict__ out)
{
    __shared__ ushortT As[64 * 40];
    __shared__ ushortT Bs[128 * 40];

    const int b  = blockIdx.x;
    const int kc = b & 3;
    const int jt = (b >> 2) & 7;
    const int rt = b >> 5;
    const int tid = threadIdx.x;
    const int r0 = rt * 64, j0 = jt * 128, k0 = kc * 256;

    const int w  = tid >> 6;        // 0..7
    const int wr = w >> 2;          // 0..1
    const int wc = w & 3;           // 0..3
    const int l  = tid & 63;
    const int lr = l & 15;
    const int lk = l >> 4;

    f32x4 c00 = {0.f, 0.f, 0.f, 0.f};
    f32x4 c01 = {0.f, 0.f, 0.f, 0.f};
    f32x4 c10 = {0.f, 0.f, 0.f, 0.f};
    f32x4 c11 = {0.f, 0.f, 0.f, 0.f};

    for (int kt = 0; kt < 8; ++kt) {
        const int kb = k0 + kt * 32;
        __syncthreads();
        {
            const int row = tid >> 3;
            const int kq  = tid & 7;
            const float4 a = *(const float4*)&AO[(size_t)(r0 + row) * EMB + kb + kq * 4];
            *(ushort4*)&As[row * 40 + kq * 4] = f2bf4(a);
        }
        {
            const int row = tid >> 2;
            const int ko  = tid & 3;
            const uint4 wv = *(const uint4*)&Wob[(size_t)(j0 + row) * EMB + kb + ko * 8];
            *(uint4*)&Bs[row * 40 + ko * 8] = wv;
        }
        __syncthreads();

        const bf16x8 a0 = *(const bf16x8*)&As[(wr * 32 + lr) * 40 + lk * 8];
        const bf16x8 a1 = *(const bf16x8*)&As[(wr * 32 + 16 + lr) * 40 + lk * 8];
        const bf16x8 b0 = *(const bf16x8*)&Bs[(wc * 32 + lr) * 40 + lk * 8];
        const bf16x8 b1 = *(const bf16x8*)&Bs[(wc * 32 + 16 + lr) * 40 + lk * 8];
        c00 = __builtin_amdgcn_mfma_f32_16x16x32_bf16(a0, b0, c00, 0, 0, 0);
        c01 = __builtin_amdgcn_mfma_f32_16x16x32_bf16(a0, b1, c01, 0, 0, 0);
        c10 = __builtin_amdgcn_mfma_f32_16x16x32_bf16(a1, b0, c10, 0, 0, 0);
        c11 = __builtin_amdgcn_mfma_f32_16x16x32_bf16(a1, b1, c11, 0, 0, 0);
    }

    const int rbase = r0 + wr * 32 + lk * 4;
    const int jbase = j0 + wc * 32 + lr;
#pragma unroll
    for (int e = 0; e < 4; ++e) {
        atomicAdd(&out[(size_t)(rbase + e) * EMB + jbase],           c00[e]);
        atomicAdd(&out[(size_t)(rbase + e) * EMB + jbase + 16],      c01[e]);
        atomicAdd(&out[(size_t)(rbase + 16 + e) * EMB + jbase],      c10[e]);
        atomicAdd(&out[(size_t)(rbase + 16 + e) * EMB + jbase + 16], c11[e]);
    }
}

extern "C" void kernel_launch(void* const* d_in, const int* in_sizes, int n_in,
                              void* d_out, int out_size, void* d_ws, size_t ws_size,
                              hipStream_t stream)
{
    const float* x  = (const float*)d_in[0];
    const float* Wq = (const float*)d_in[1];
    const float* Wk = (const float*)d_in[2];
    const float* Wv = (const float*)d_in[3];
    const float* Wo = (const float*)d_in[4];
    const float* bo = (const float*)d_in[5];

    float* ws = (float*)d_ws;
    ushortT* Q   = (ushortT*)ws;              // 524288 bf16 = 1 MB
    ushortT* K   = (ushortT*)(ws + 262144);   // 1 MB
    ushortT* V   = (ushortT*)(ws + 524288);   // 1 MB
    float*   AO  = ws + 786432;               // 524288 f32 = 2 MB
    ushortT* Wob = (ushortT*)(ws + 1310720);  // 1048576 bf16 = 2 MB

    qkv_kernel<<<256, 256, 0, stream>>>(x, Wq, Wk, Wv, Wo, bo, Q, K, V, AO,
                                        (float*)d_out, Wob);
    attn_kernel<<<1024, 256, 0, stream>>>(Q, K, V, AO);
    proj_kernel<<<256, 512, 0, stream>>>(AO, Wob, (float*)d_out);
}